// Round 3
// baseline (174.200 us; speedup 1.0000x reference)
//
#include <hip/hip_runtime.h>
#include <hip/hip_bf16.h>

#define DEVINL __device__ __forceinline__

typedef __attribute__((ext_vector_type(8)))  short short8;
typedef __attribute__((ext_vector_type(4)))  float float4v;

DEVINL float bf2f(unsigned short u) { return __uint_as_float(((unsigned)u) << 16); }
DEVINL unsigned short f2bf(float f) {            // round-to-nearest-even
  unsigned u = __float_as_uint(f);
  unsigned r = u + 0x7FFFu + ((u >> 16) & 1u);
  return (unsigned short)(r >> 16);
}

// region: 0=center,1=TL,2=top,3=TR,4=right,5=BR,6=bottom,7=BL,8=left
DEVINL int region_of(int h, int w, int n) {
  if (h == 0)     return (w == 0) ? 1 : ((w == n-1) ? 3 : 2);
  if (h == n-1)   return (w == 0) ? 7 : ((w == n-1) ? 5 : 6);
  return (w == 0) ? 8 : ((w == n-1) ? 4 : 0);
}

// ---- sentinel: encodes an environment-assumption failure into d_out ----
__global__ void sentinel_k(float* out, float v) {
  int t = blockIdx.x*64 + threadIdx.x;
  if (t < 320) out[t] = v;
}

// ---- weight transpose into MFMA B-fragment layout, fp32 -> bf16 (3 tensors) ----
// B-frag (16x16x32): lane holds B[k = (lane>>4)*8 + j][n = lane&15], j=0..7.
__global__ void wtrans_all(const float* __restrict__ W2, const float* __restrict__ W3,
                           const float* __restrict__ W4,
                           unsigned short* __restrict__ T2, unsigned short* __restrict__ T3,
                           unsigned short* __restrict__ T4)
{
  int y = blockIdx.y;
  const float* W = (y == 0) ? W2 : (y == 1) ? W3 : W4;
  unsigned short* T = (y == 0) ? T2 : (y == 1) ? T3 : T4;
  int Ksteps = (y == 2) ? 36 : 18;
  int NT = (y == 0) ? 4 : 8;
  int F  = (y == 0) ? 64 : 128;
  int i = blockIdx.x*256 + threadIdx.x;
  if (i >= Ksteps*NT*64) return;
  int lane = i & 63, nt = (i >> 6) % NT, kstep = i / (64*NT);
  int f = nt*16 + (lane & 15);
  int kbase = kstep*32 + (lane >> 4)*8;
  unsigned short v[8];
  #pragma unroll
  for (int j = 0; j < 8; j++) v[j] = f2bf(W[(kbase + j)*F + f]);
  ushort4* q = (ushort4*)&T[(size_t)i * 8];
  q[0] = make_ushort4(v[0], v[1], v[2], v[3]);
  q[1] = make_ushort4(v[4], v[5], v[6], v[7]);
}

// ---- FUSED conv1 (vector ALU, 1->64) + conv2 MFMA (64->64) + 2x2 pool ----
__global__ __launch_bounds__(256) void conv12_k(const float* __restrict__ x,
    const float* __restrict__ Wf1, const float* __restrict__ Df1,
    const unsigned short* __restrict__ Wt, const float* __restrict__ Df2,
    unsigned short* __restrict__ out)
{
  constexpr int Cpad = 72;                     // 64 + 8: 16B-aligned rows
  __shared__ __align__(16) unsigned short u[4*66*Cpad];   // U1 rows h0-1..h0+2
  __shared__ float xs[6][66];                  // x rows h0-2..h0+3, w -1..64

  int b = blockIdx.y, hp = blockIdx.x, t = threadIdx.x;
  int h0 = hp * 2;

  // stage x (zero halo)
  for (int idx = t; idx < 6*66; idx += 256) {
    int r = idx / 66, wc = idx % 66;
    int hh = h0 - 2 + r, w = wc - 1;
    float v = 0.f;
    if (hh >= 0 && hh < 64 && w >= 0 && w < 64) v = x[(b*64 + hh)*64 + w];
    xs[r][wc] = v;
  }
  __syncthreads();

  // conv1 into LDS: 8 groups = (row r 0..3) x (w-half wh 0..1); 2 f per thread.
  {
    int f2 = (t & 31) * 2, g = t >> 5;
    int r = g & 3, wh = g >> 2;
    int hh = h0 - 1 + r;
    bool valid = (hh >= 0 && hh < 64);
    float wka[9], wkb[9];
    #pragma unroll
    for (int k = 0; k < 9; k++) {
      wka[k] = Wf1[k*64 + f2];
      wkb[k] = Wf1[k*64 + f2 + 1];
    }
    int w0 = wh * 32;
    float cA0 = xs[r+0][w0], cA1 = xs[r+1][w0], cA2 = xs[r+2][w0];
    float cB0 = xs[r+0][w0+1], cB1 = xs[r+1][w0+1], cB2 = xs[r+2][w0+1];
    for (int wi = 0; wi < 32; wi++) {
      int w = w0 + wi;
      float cC0 = xs[r+0][w+2], cC1 = xs[r+1][w+2], cC2 = xs[r+2][w+2];
      float aa = cA0*wka[0] + cB0*wka[1] + cC0*wka[2]
               + cA1*wka[3] + cB1*wka[4] + cC1*wka[5]
               + cA2*wka[6] + cB2*wka[7] + cC2*wka[8];
      float ab = cA0*wkb[0] + cB0*wkb[1] + cC0*wkb[2]
               + cA1*wkb[3] + cB1*wkb[4] + cC1*wkb[5]
               + cA2*wkb[6] + cB2*wkb[7] + cC2*wkb[8];
      float va = 0.f, vb = 0.f;
      if (valid) {
        int reg = region_of(hh, w, 64);
        va = fminf(aa - Df1[reg*64 + f2],     0.f);
        vb = fminf(ab - Df1[reg*64 + f2 + 1], 0.f);
      }
      unsigned pk = (unsigned)f2bf(va) | ((unsigned)f2bf(vb) << 16);
      *(unsigned*)&u[(r*66 + (w+1))*Cpad + f2] = pk;
      cA0 = cB0; cB0 = cC0; cA1 = cB1; cB1 = cC1; cA2 = cB2; cB2 = cC2;
    }
    *(unsigned*)&u[(r*66 + (wh ? 65 : 0))*Cpad + f2] = 0u;
  }
  __syncthreads();

  // conv2 MFMA: C=64,F=64,N=64,POOL,WSM=2 -> MW=2,NW=2,RC=2
  int lane = t & 63, wave = t >> 6;
  int wm = wave >> 1, wn = wave & 1;
  int quad = lane >> 4, lm = lane & 15;

  union ABu { float4 f4; short8 v; };

  float4v acc[2][2][2];
  #pragma unroll
  for (int hi = 0; hi < 2; hi++)
    #pragma unroll
    for (int m = 0; m < 2; m++)
      #pragma unroll
      for (int n = 0; n < 2; n++)
        acc[hi][m][n] = (float4v){0.f, 0.f, 0.f, 0.f};

  #pragma unroll
  for (int dy = 0; dy < 3; dy++)
  #pragma unroll
  for (int dx = 0; dx < 3; dx++)
  #pragma unroll
  for (int c0 = 0; c0 < 64; c0 += 32) {
    int kstep = (dy*3 + dx)*2 + (c0 >> 5);
    ABu bfr[2];
    #pragma unroll
    for (int n = 0; n < 2; n++)
      bfr[n].f4 = *(const float4*)&Wt[(size_t)((kstep*4 + wn*2 + n)*64 + lane)*8];
    #pragma unroll
    for (int hi = 0; hi < 2; hi++) {
      ABu afr[2];
      #pragma unroll
      for (int m = 0; m < 2; m++)
        afr[m].f4 = *(const float4*)&u[((hi+dy)*66 + ((wm*2 + m)*16 + lm + dx))*Cpad + c0 + quad*8];
      #pragma unroll
      for (int n = 0; n < 2; n++)
        #pragma unroll
        for (int m = 0; m < 2; m++)
          acc[hi][m][n] = __builtin_amdgcn_mfma_f32_16x16x32_bf16(afr[m].v, bfr[n].v, acc[hi][m][n], 0, 0, 0);
    }
  }

  #pragma unroll
  for (int m = 0; m < 2; m++)
    #pragma unroll
    for (int n = 0; n < 2; n++) {
      int mm = wm*2 + m;
      int f = (wn*2 + n)*16 + lm;
      #pragma unroll
      for (int rp = 0; rp < 2; rp++) {
        float mx = -1e30f;
        #pragma unroll
        for (int hi = 0; hi < 2; hi++)
          #pragma unroll
          for (int rr = 0; rr < 2; rr++) {
            int h = h0 + hi, w = mm*16 + quad*4 + 2*rp + rr;
            float v = fminf(acc[hi][m][n][2*rp+rr] - Df2[region_of(h, w, 64)*64 + f], 0.f);
            mx = fmaxf(mx, v);
          }
        int wp = mm*8 + quad*2 + rp;
        out[(((size_t)b*32 + hp)*32 + wp)*64 + f] = f2bf(mx);
      }
    }
}

// ---- FUSED conv3 (64->128) + conv4 (128->128) + 2x2 pool ----
// Block (hp4, b): stages P2 rows 2hp4-2..2hp4+3 (29KB), computes u3 rows
// 2hp4-1..2hp4+2 in LDS (37KB, 2x row redundancy vs separate kernels, MFMA pipe
// is cheap), then conv4+pool -> P4 row hp4. Removes U3 8.4MB write + ~17MB
// halo re-read + one launch. 65KB LDS -> 2 blocks/CU.
__global__ __launch_bounds__(256) void conv34_k(
    const unsigned short* __restrict__ P2, const unsigned short* __restrict__ Wt3,
    const float* __restrict__ Df3, const unsigned short* __restrict__ Wt4,
    const float* __restrict__ Df4, unsigned short* __restrict__ out)
{
  __shared__ __align__(16) unsigned short p2[6*34*72];    // P2 rows, Cpad=72
  __shared__ __align__(16) unsigned short u3[4*34*136];   // u3 rows, Cpad=136

  int b = blockIdx.y, hp4 = blockIdx.x, t = threadIdx.x;
  int h30 = hp4*2 - 1;                 // u3 rows h30 .. h30+3

  // stage P2 rows h30-1 .. h30+4, zero halo
  #pragma unroll 4
  for (int i = t; i < 6*34*8; i += 256) {
    int c8 = i & 7, wc = (i >> 3) % 34, r = i / (8*34);
    int hh = h30 - 1 + r, w = wc - 1;
    float4 v = make_float4(0.f,0.f,0.f,0.f);
    if (hh >= 0 && hh < 32 && w >= 0 && w < 32)
      v = *(const float4*)&P2[(((size_t)b*32 + hh)*32 + w)*64 + c8*8];
    *(float4*)&p2[(r*34 + wc)*72 + c8*8] = v;
  }
  // zero u3 (halo cols + invalid rows stay zero)
  for (int i = t; i < 4*34*136/2; i += 256) ((unsigned*)u3)[i] = 0u;
  __syncthreads();

  int lane = t & 63, wave = t >> 6;
  int quad = lane >> 4, lm = lane & 15;
  union ABu { float4 f4; short8 v; };

  // ---- phase A: conv3 for 4 u3 rows; wave owns n-tiles wave*2+{0,1} ----
  {
    float4v acc[4][2][2];
    #pragma unroll
    for (int r = 0; r < 4; r++)
      #pragma unroll
      for (int m = 0; m < 2; m++)
        #pragma unroll
        for (int n = 0; n < 2; n++)
          acc[r][m][n] = (float4v){0.f,0.f,0.f,0.f};

    #pragma unroll
    for (int dy = 0; dy < 3; dy++)
    #pragma unroll
    for (int dx = 0; dx < 3; dx++)
    #pragma unroll
    for (int c0 = 0; c0 < 64; c0 += 32) {
      int kstep = (dy*3+dx)*2 + (c0 >> 5);
      ABu bfr[2];
      #pragma unroll
      for (int n = 0; n < 2; n++)
        bfr[n].f4 = *(const float4*)&Wt3[(size_t)((kstep*8 + wave*2 + n)*64 + lane)*8];
      #pragma unroll
      for (int r = 0; r < 4; r++) {
        ABu afr[2];
        #pragma unroll
        for (int m = 0; m < 2; m++)
          afr[m].f4 = *(const float4*)&p2[((r+dy)*34 + (m*16 + lm + dx))*72 + c0 + quad*8];
        #pragma unroll
        for (int n = 0; n < 2; n++)
          #pragma unroll
          for (int m = 0; m < 2; m++)
            acc[r][m][n] = __builtin_amdgcn_mfma_f32_16x16x32_bf16(afr[m].v, bfr[n].v, acc[r][m][n], 0,0,0);
      }
    }
    #pragma unroll
    for (int r = 0; r < 4; r++) {
      int h3 = h30 + r;
      if (h3 >= 0 && h3 < 32) {
        #pragma unroll
        for (int m = 0; m < 2; m++)
          #pragma unroll
          for (int n = 0; n < 2; n++) {
            int f = (wave*2 + n)*16 + lm;
            #pragma unroll
            for (int rr = 0; rr < 4; rr++) {
              int w = m*16 + quad*4 + rr;
              float v = fminf(acc[r][m][n][rr] - Df3[region_of(h3, w, 32)*128 + f], 0.f);
              u3[(r*34 + (w+1))*136 + f] = f2bf(v);
            }
          }
      }
    }
  }
  __syncthreads();

  // ---- phase B: conv4 + pool, u4 rows 2hp4, 2hp4+1 (local u3 rows hi+dy) ----
  {
    int wn = wave;                       // 4-way n-split, NW=2
    int h0 = hp4*2;
    float4v acc[2][2][2];
    #pragma unroll
    for (int hi = 0; hi < 2; hi++)
      #pragma unroll
      for (int m = 0; m < 2; m++)
        #pragma unroll
        for (int n = 0; n < 2; n++)
          acc[hi][m][n] = (float4v){0.f,0.f,0.f,0.f};

    #pragma unroll
    for (int dy = 0; dy < 3; dy++)
    #pragma unroll
    for (int dx = 0; dx < 3; dx++)
    #pragma unroll
    for (int c0 = 0; c0 < 128; c0 += 32) {
      int kstep = (dy*3+dx)*4 + (c0 >> 5);
      ABu bfr[2];
      #pragma unroll
      for (int n = 0; n < 2; n++)
        bfr[n].f4 = *(const float4*)&Wt4[(size_t)((kstep*8 + wn*2 + n)*64 + lane)*8];
      #pragma unroll
      for (int hi = 0; hi < 2; hi++) {
        ABu afr[2];
        #pragma unroll
        for (int m = 0; m < 2; m++)
          afr[m].f4 = *(const float4*)&u3[((hi+dy)*34 + (m*16 + lm + dx))*136 + c0 + quad*8];
        #pragma unroll
        for (int n = 0; n < 2; n++)
          #pragma unroll
          for (int m = 0; m < 2; m++)
            acc[hi][m][n] = __builtin_amdgcn_mfma_f32_16x16x32_bf16(afr[m].v, bfr[n].v, acc[hi][m][n], 0,0,0);
      }
    }

    #pragma unroll
    for (int m = 0; m < 2; m++)
      #pragma unroll
      for (int n = 0; n < 2; n++) {
        int f = (wn*2 + n)*16 + lm;
        #pragma unroll
        for (int rp = 0; rp < 2; rp++) {
          float mx = -1e30f;
          #pragma unroll
          for (int hi = 0; hi < 2; hi++)
            #pragma unroll
            for (int rr = 0; rr < 2; rr++) {
              int h = h0 + hi, w = m*16 + quad*4 + 2*rp + rr;
              float v = fminf(acc[hi][m][n][2*rp+rr] - Df4[region_of(h, w, 32)*128 + f], 0.f);
              mx = fmaxf(mx, v);
            }
          int wp = m*8 + quad*2 + rp;
          out[(((size_t)b*16 + hp4)*16 + wp)*128 + f] = f2bf(mx);
        }
      }
  }
}

// ---- dense1 split-K + f-split: act bf16 [32,32768], Wd1 fp32 -> fp32 partials ----
// unroll 16: W is L3-resident (33.5MB); deeper MLP exploits L3 BW > HBM rate.
__global__ __launch_bounds__(256) void dense_k(const unsigned short* __restrict__ act,
    const float* __restrict__ W, float* __restrict__ part)
{
  int blk = blockIdx.x, t = threadIdx.x;
  int kblk = blk >> 1, fh = blk & 1;
  int k0 = kblk * 128;
  __shared__ float a[128][36];             // [kc][b], padded
  for (int idx = t; idx < 32*128; idx += 256) {
    int bb = idx >> 7, kc = idx & 127;
    a[kc][bb] = bf2f(act[(size_t)bb*32768 + k0 + kc]);
  }
  __syncthreads();
  int f0 = fh*128 + (t & 31)*4, b0 = (t >> 5)*4;   // 4f x 4b per thread
  float acc[4][4] = {};
  #pragma unroll 16
  for (int kc = 0; kc < 128; kc++) {
    float4 wv = *(const float4*)&W[(size_t)(k0 + kc)*256 + f0];
    float4 av = *(const float4*)&a[kc][b0];
    const float* avp = (const float*)&av;
    #pragma unroll
    for (int bb = 0; bb < 4; bb++) {
      float avx = avp[bb];
      acc[bb][0] += avx * wv.x;
      acc[bb][1] += avx * wv.y;
      acc[bb][2] += avx * wv.z;
      acc[bb][3] += avx * wv.w;
    }
  }
  #pragma unroll
  for (int bb = 0; bb < 4; bb++) {
    float4 v = make_float4(acc[bb][0], acc[bb][1], acc[bb][2], acc[bb][3]);
    *(float4*)&part[(size_t)kblk*8192 + (b0+bb)*256 + f0] = v;
  }
}

// ---- FUSED reduce + output: one block per batch row b (32 blocks x 1024 thr) ----
__global__ __launch_bounds__(1024) void redfin_k(const float* __restrict__ part,
    const float* __restrict__ Dd, const float* __restrict__ Wo,
    const float* __restrict__ Do, float* __restrict__ out)
{
  int b = blockIdx.x, t = threadIdx.x;
  int f = t & 255, kq = t >> 8;            // 4 k-quarters x 256 f
  float s = 0.f;
  #pragma unroll 16
  for (int blk = kq*64; blk < kq*64 + 64; blk++)
    s += part[(size_t)blk*8192 + b*256 + f];
  __shared__ float red[4][256];
  red[kq][f] = s;
  __syncthreads();
  __shared__ float ud[256];
  if (t < 256) {
    float v = red[0][t] + red[1][t] + red[2][t] + red[3][t];
    ud[t] = fminf(v - Dd[t], 0.f);
  }
  __syncthreads();
  int lane = t & 63, wave = t >> 6;
  if (wave < 4) {
    for (int o = wave; o < 10; o += 4) {
      float acc = 0.f;
      #pragma unroll
      for (int j = 0; j < 4; j++) {
        int ff = j*64 + lane;
        acc += ud[ff] * Wo[ff*10 + o];
      }
      #pragma unroll
      for (int off = 32; off; off >>= 1) acc += __shfl_down(acc, off, 64);
      if (lane == 0) out[b*10 + o] = Do[o] - acc;
    }
  }
}

extern "C" void kernel_launch(void* const* d_in, const int* in_sizes, int n_in,
                              void* d_out, int out_size, void* d_ws, size_t ws_size,
                              hipStream_t stream)
{
  float* outp = (float*)d_out;

  if (n_in != 13) { sentinel_k<<<5, 64, 0, stream>>>(outp, 200.f); return; }
  const int exp_sz[13] = {131072, 576, 576, 36864, 576, 73728, 1152,
                          147456, 1152, 8388608, 256, 2560, 10};
  for (int i = 0; i < 13; i++)
    if (in_sizes[i] != exp_sz[i]) {
      sentinel_k<<<5, 64, 0, stream>>>(outp, 1000.f + 100.f*i); return;
    }
  if (ws_size < (37u << 20)) { sentinel_k<<<5, 64, 0, stream>>>(outp, 500.f); return; }

  char* wsb = (char*)d_ws;
  const float* x    = (const float*)d_in[0];
  const float* Wc1  = (const float*)d_in[1];
  const float* Dc1  = (const float*)d_in[2];
  const float* Wc2  = (const float*)d_in[3];
  const float* Dc2  = (const float*)d_in[4];
  const float* Wc3  = (const float*)d_in[5];
  const float* Dc3  = (const float*)d_in[6];
  const float* Wc4  = (const float*)d_in[7];
  const float* Dc4  = (const float*)d_in[8];
  const float* Wd1  = (const float*)d_in[9];
  const float* Dd1  = (const float*)d_in[10];
  const float* Wout = (const float*)d_in[11];
  const float* Dout = (const float*)d_in[12];

  // ws layout (lifetime-safe):
  //   [1.0,1.8 MiB): Wt2/Wt3/Wt4 | part=[2,11 MiB) | P2=[19,23.2) | P4=[25,27.1)
  // conv34 reads P2(19M) writes P4(25M) - disjoint. dense reads P4 writes part(2M).
  unsigned short* Wt2 = (unsigned short*)(wsb + (1u << 20));
  unsigned short* Wt3 = (unsigned short*)(wsb + (1u << 20) + 262144);
  unsigned short* Wt4 = (unsigned short*)(wsb + (1u << 20) + 524288);
  unsigned short* P2  = (unsigned short*)(wsb + (19u << 20)); // 4.2 MB (conv12 out)
  unsigned short* P4  = (unsigned short*)(wsb + (25u << 20)); // 2.1 MB (conv34 out)
  float* part         = (float*)(wsb + (2u  << 20));          // 8.4 MB

  wtrans_all<<<dim3(72, 3), 256, 0, stream>>>(Wc2, Wc3, Wc4, Wt2, Wt3, Wt4);
  conv12_k<<<dim3(32, 32), 256, 0, stream>>>(x, Wc1, Dc1, Wt2, Dc2, P2);
  conv34_k<<<dim3(16, 32), 256, 0, stream>>>(P2, Wt3, Dc3, Wt4, Dc4, P4);
  dense_k<<<512, 256, 0, stream>>>(P4, Wd1, part);
  redfin_k<<<32, 1024, 0, stream>>>(part, Dd1, Wout, Dout, outp);
}

// Round 5
// 169.866 us; speedup vs baseline: 1.0255x; 1.0255x over previous
//
#include <hip/hip_runtime.h>
#include <hip/hip_bf16.h>

#define DEVINL __device__ __forceinline__

typedef __attribute__((ext_vector_type(8)))  short short8;
typedef __attribute__((ext_vector_type(4)))  float float4v;

DEVINL float bf2f(unsigned short u) { return __uint_as_float(((unsigned)u) << 16); }
DEVINL unsigned short f2bf(float f) {            // round-to-nearest-even
  unsigned u = __float_as_uint(f);
  unsigned r = u + 0x7FFFu + ((u >> 16) & 1u);
  return (unsigned short)(r >> 16);
}

// region: 0=center,1=TL,2=top,3=TR,4=right,5=BR,6=bottom,7=BL,8=left
DEVINL int region_of(int h, int w, int n) {
  if (h == 0)     return (w == 0) ? 1 : ((w == n-1) ? 3 : 2);
  if (h == n-1)   return (w == 0) ? 7 : ((w == n-1) ? 5 : 6);
  return (w == 0) ? 8 : ((w == n-1) ? 4 : 0);
}

// ---- sentinel: encodes an environment-assumption failure into d_out ----
__global__ void sentinel_k(float* out, float v) {
  int t = blockIdx.x*64 + threadIdx.x;
  if (t < 320) out[t] = v;
}

// ---- weight transpose into MFMA B-fragment layout, fp32 -> bf16 (3 tensors) ----
// B-frag (16x16x32): lane holds B[k = (lane>>4)*8 + j][n = lane&15], j=0..7.
__global__ void wtrans_all(const float* __restrict__ W2, const float* __restrict__ W3,
                           const float* __restrict__ W4,
                           unsigned short* __restrict__ T2, unsigned short* __restrict__ T3,
                           unsigned short* __restrict__ T4)
{
  int y = blockIdx.y;
  const float* W = (y == 0) ? W2 : (y == 1) ? W3 : W4;
  unsigned short* T = (y == 0) ? T2 : (y == 1) ? T3 : T4;
  int Ksteps = (y == 2) ? 36 : 18;
  int NT = (y == 0) ? 4 : 8;
  int F  = (y == 0) ? 64 : 128;
  int i = blockIdx.x*256 + threadIdx.x;
  if (i >= Ksteps*NT*64) return;
  int lane = i & 63, nt = (i >> 6) % NT, kstep = i / (64*NT);
  int f = nt*16 + (lane & 15);
  int kbase = kstep*32 + (lane >> 4)*8;
  unsigned short v[8];
  #pragma unroll
  for (int j = 0; j < 8; j++) v[j] = f2bf(W[(kbase + j)*F + f]);
  ushort4* q = (ushort4*)&T[(size_t)i * 8];
  q[0] = make_ushort4(v[0], v[1], v[2], v[3]);
  q[1] = make_ushort4(v[4], v[5], v[6], v[7]);
}

// ---- FUSED conv1 (vector ALU, 1->64) + conv2 MFMA (64->64) + 2x2 pool ----
// conv2 wave split (R4): wave owns ONE m-tile (16 w), both h-rows, ALL F.
// Per kstep: 2 A ds_read_b128 + 4 B global(L1/L2) + 8 MFMA -> MFMA-bound
// (was 4 A + 2 B + 8 MFMA = LDS-issue-bound).
__global__ __launch_bounds__(256) void conv12_k(const float* __restrict__ x,
    const float* __restrict__ Wf1, const float* __restrict__ Df1,
    const unsigned short* __restrict__ Wt, const float* __restrict__ Df2,
    unsigned short* __restrict__ out)
{
  constexpr int Cpad = 72;                     // 64 + 8: 16B-aligned rows
  __shared__ __align__(16) unsigned short u[4*66*Cpad];   // U1 rows h0-1..h0+2
  __shared__ float xs[6][66];                  // x rows h0-2..h0+3, w -1..64

  int b = blockIdx.y, hp = blockIdx.x, t = threadIdx.x;
  int h0 = hp * 2;

  // stage x (zero halo)
  for (int idx = t; idx < 6*66; idx += 256) {
    int r = idx / 66, wc = idx % 66;
    int hh = h0 - 2 + r, w = wc - 1;
    float v = 0.f;
    if (hh >= 0 && hh < 64 && w >= 0 && w < 64) v = x[(b*64 + hh)*64 + w];
    xs[r][wc] = v;
  }
  __syncthreads();

  // conv1 into LDS: 8 groups = (row r 0..3) x (w-half wh 0..1); 2 f per thread.
  {
    int f2 = (t & 31) * 2, g = t >> 5;
    int r = g & 3, wh = g >> 2;
    int hh = h0 - 1 + r;
    bool valid = (hh >= 0 && hh < 64);
    float wka[9], wkb[9];
    #pragma unroll
    for (int k = 0; k < 9; k++) {
      wka[k] = Wf1[k*64 + f2];
      wkb[k] = Wf1[k*64 + f2 + 1];
    }
    int w0 = wh * 32;
    float cA0 = xs[r+0][w0], cA1 = xs[r+1][w0], cA2 = xs[r+2][w0];
    float cB0 = xs[r+0][w0+1], cB1 = xs[r+1][w0+1], cB2 = xs[r+2][w0+1];
    for (int wi = 0; wi < 32; wi++) {
      int w = w0 + wi;
      float cC0 = xs[r+0][w+2], cC1 = xs[r+1][w+2], cC2 = xs[r+2][w+2];
      float aa = cA0*wka[0] + cB0*wka[1] + cC0*wka[2]
               + cA1*wka[3] + cB1*wka[4] + cC1*wka[5]
               + cA2*wka[6] + cB2*wka[7] + cC2*wka[8];
      float ab = cA0*wkb[0] + cB0*wkb[1] + cC0*wkb[2]
               + cA1*wkb[3] + cB1*wkb[4] + cC1*wkb[5]
               + cA2*wkb[6] + cB2*wkb[7] + cC2*wkb[8];
      float va = 0.f, vb = 0.f;
      if (valid) {
        int reg = region_of(hh, w, 64);
        va = fminf(aa - Df1[reg*64 + f2],     0.f);
        vb = fminf(ab - Df1[reg*64 + f2 + 1], 0.f);
      }
      unsigned pk = (unsigned)f2bf(va) | ((unsigned)f2bf(vb) << 16);
      *(unsigned*)&u[(r*66 + (w+1))*Cpad + f2] = pk;
      cA0 = cB0; cB0 = cC0; cA1 = cB1; cB1 = cC1; cA2 = cB2; cB2 = cC2;
    }
    *(unsigned*)&u[(r*66 + (wh ? 65 : 0))*Cpad + f2] = 0u;
  }
  __syncthreads();

  // conv2 MFMA: wave m = wave (m-tile), acc[hi][n] over all F (NT=4)
  int lane = t & 63, wave = t >> 6;
  int quad = lane >> 4, lm = lane & 15;

  union ABu { float4 f4; short8 v; };

  float4v acc[2][4];
  #pragma unroll
  for (int hi = 0; hi < 2; hi++)
    #pragma unroll
    for (int n = 0; n < 4; n++)
      acc[hi][n] = (float4v){0.f, 0.f, 0.f, 0.f};

  #pragma unroll
  for (int dy = 0; dy < 3; dy++)
  #pragma unroll
  for (int dx = 0; dx < 3; dx++)
  #pragma unroll
  for (int c0 = 0; c0 < 64; c0 += 32) {
    int kstep = (dy*3 + dx)*2 + (c0 >> 5);
    ABu bfr[4];
    #pragma unroll
    for (int n = 0; n < 4; n++)
      bfr[n].f4 = *(const float4*)&Wt[(size_t)((kstep*4 + n)*64 + lane)*8];
    ABu afr[2];
    #pragma unroll
    for (int hi = 0; hi < 2; hi++)
      afr[hi].f4 = *(const float4*)&u[((hi+dy)*66 + (wave*16 + lm + dx))*Cpad + c0 + quad*8];
    #pragma unroll
    for (int hi = 0; hi < 2; hi++)
      #pragma unroll
      for (int n = 0; n < 4; n++)
        acc[hi][n] = __builtin_amdgcn_mfma_f32_16x16x32_bf16(afr[hi].v, bfr[n].v, acc[hi][n], 0, 0, 0);
  }

  // epilogue + pool: D layout col=lane&15 (f), row=quad*4+r (w); wave = m-tile
  #pragma unroll
  for (int n = 0; n < 4; n++) {
    int f = n*16 + lm;
    #pragma unroll
    for (int rp = 0; rp < 2; rp++) {
      float mx = -1e30f;
      #pragma unroll
      for (int hi = 0; hi < 2; hi++)
        #pragma unroll
        for (int rr = 0; rr < 2; rr++) {
          int h = h0 + hi, w = wave*16 + quad*4 + 2*rp + rr;
          float v = fminf(acc[hi][n][2*rp+rr] - Df2[region_of(h, w, 64)*64 + f], 0.f);
          mx = fmaxf(mx, v);
        }
      int wp = wave*8 + quad*2 + rp;
      out[(((size_t)b*32 + hp)*32 + wp)*64 + f] = f2bf(mx);
    }
  }
}

// ---- conv3/conv4 (separate; R3 fusion regressed): F=128, N=32, 2 rows/block ----
// Wave = (m-tile = wave>>1, f-half = wave&1); per kstep: 2 A ds_read + 4 B
// global + 8 MFMA (MFMA-bound).
template<int C, bool POOL>
__global__ __launch_bounds__(256) void conv_hf(
    const unsigned short* __restrict__ U, const unsigned short* __restrict__ Wt,
    const float* __restrict__ Df, unsigned short* __restrict__ out)
{
  constexpr int Cpad = C + 8;

  __shared__ __align__(16) unsigned short lds[4*34*Cpad];

  int b = blockIdx.y, hp = blockIdx.x, t = threadIdx.x;
  int h0 = hp * 2;

  const int stage16 = 4*34*(C/8);
  #pragma unroll 4
  for (int i = t; i < stage16; i += 256) {
    int c8 = i % (C/8), wc = (i/(C/8)) % 34, r = i/((C/8)*34);
    int hh = h0 - 1 + r, w = wc - 1;
    float4 v = make_float4(0.f,0.f,0.f,0.f);
    if (hh >= 0 && hh < 32 && w >= 0 && w < 32)
      v = *(const float4*)&U[(((size_t)b*32 + hh)*32 + w)*C + c8*8];
    *(float4*)&lds[(r*34 + wc)*Cpad + c8*8] = v;
  }
  __syncthreads();

  int lane = t & 63, wave = t >> 6;
  int m = wave >> 1, fh = wave & 1;
  int quad = lane >> 4, lm = lane & 15;
  union ABu { float4 f4; short8 v; };

  float4v acc[2][4];
  #pragma unroll
  for (int hi = 0; hi < 2; hi++)
    #pragma unroll
    for (int n = 0; n < 4; n++)
      acc[hi][n] = (float4v){0.f, 0.f, 0.f, 0.f};

  #pragma unroll
  for (int dy = 0; dy < 3; dy++)
  #pragma unroll
  for (int dx = 0; dx < 3; dx++)
  #pragma unroll
  for (int c0 = 0; c0 < C; c0 += 32) {
    int kstep = (dy*3 + dx)*(C/32) + (c0 >> 5);
    ABu bfr[4];
    #pragma unroll
    for (int n = 0; n < 4; n++)
      bfr[n].f4 = *(const float4*)&Wt[(size_t)((kstep*8 + fh*4 + n)*64 + lane)*8];
    ABu afr[2];
    #pragma unroll
    for (int hi = 0; hi < 2; hi++)
      afr[hi].f4 = *(const float4*)&lds[((hi+dy)*34 + (m*16 + lm + dx))*Cpad + c0 + quad*8];
    #pragma unroll
    for (int hi = 0; hi < 2; hi++)
      #pragma unroll
      for (int n = 0; n < 4; n++)
        acc[hi][n] = __builtin_amdgcn_mfma_f32_16x16x32_bf16(afr[hi].v, bfr[n].v, acc[hi][n], 0, 0, 0);
  }

  if constexpr (POOL) {
    #pragma unroll
    for (int n = 0; n < 4; n++) {
      int f = fh*64 + n*16 + lm;
      #pragma unroll
      for (int rp = 0; rp < 2; rp++) {
        float mx = -1e30f;
        #pragma unroll
        for (int hi = 0; hi < 2; hi++)
          #pragma unroll
          for (int rr = 0; rr < 2; rr++) {
            int h = h0 + hi, w = m*16 + quad*4 + 2*rp + rr;
            float v = fminf(acc[hi][n][2*rp+rr] - Df[region_of(h, w, 32)*128 + f], 0.f);
            mx = fmaxf(mx, v);
          }
        int wp = m*8 + quad*2 + rp;
        out[(((size_t)b*16 + hp)*16 + wp)*128 + f] = f2bf(mx);
      }
    }
  } else {
    #pragma unroll
    for (int hi = 0; hi < 2; hi++) {
      int h = h0 + hi;
      #pragma unroll
      for (int n = 0; n < 4; n++) {
        int f = fh*64 + n*16 + lm;
        #pragma unroll
        for (int r = 0; r < 4; r++) {
          int w = m*16 + quad*4 + r;
          float v = fminf(acc[hi][n][r] - Df[region_of(h, w, 32)*128 + f], 0.f);
          out[(((size_t)b*32 + h)*32 + w)*128 + f] = f2bf(v);
        }
      }
    }
  }
}

// ---- dense1 split-K + f-split: act bf16 [32,32768], Wd1 fp32 -> fp32 partials ----
__global__ __launch_bounds__(256) void dense_k(const unsigned short* __restrict__ act,
    const float* __restrict__ W, float* __restrict__ part)
{
  int blk = blockIdx.x, t = threadIdx.x;
  int kblk = blk >> 1, fh = blk & 1;
  int k0 = kblk * 128;
  __shared__ float a[128][36];             // [kc][b], padded
  for (int idx = t; idx < 32*128; idx += 256) {
    int bb = idx >> 7, kc = idx & 127;
    a[kc][bb] = bf2f(act[(size_t)bb*32768 + k0 + kc]);
  }
  __syncthreads();
  int f0 = fh*128 + (t & 31)*4, b0 = (t >> 5)*4;   // 4f x 4b per thread
  float acc[4][4] = {};
  #pragma unroll 16
  for (int kc = 0; kc < 128; kc++) {
    float4 wv = *(const float4*)&W[(size_t)(k0 + kc)*256 + f0];
    float4 av = *(const float4*)&a[kc][b0];
    const float* avp = (const float*)&av;
    #pragma unroll
    for (int bb = 0; bb < 4; bb++) {
      float avx = avp[bb];
      acc[bb][0] += avx * wv.x;
      acc[bb][1] += avx * wv.y;
      acc[bb][2] += avx * wv.z;
      acc[bb][3] += avx * wv.w;
    }
  }
  #pragma unroll
  for (int bb = 0; bb < 4; bb++) {
    float4 v = make_float4(acc[bb][0], acc[bb][1], acc[bb][2], acc[bb][3]);
    *(float4*)&part[(size_t)kblk*8192 + (b0+bb)*256 + f0] = v;
  }
}

// ---- FUSED reduce + output: one block per batch row b (32 blocks x 1024 thr) ----
__global__ __launch_bounds__(1024) void redfin_k(const float* __restrict__ part,
    const float* __restrict__ Dd, const float* __restrict__ Wo,
    const float* __restrict__ Do, float* __restrict__ out)
{
  int b = blockIdx.x, t = threadIdx.x;
  int f = t & 255, kq = t >> 8;            // 4 k-quarters x 256 f
  float s = 0.f;
  #pragma unroll 16
  for (int blk = kq*64; blk < kq*64 + 64; blk++)
    s += part[(size_t)blk*8192 + b*256 + f];
  __shared__ float red[4][256];
  red[kq][f] = s;
  __syncthreads();
  __shared__ float ud[256];
  if (t < 256) {
    float v = red[0][t] + red[1][t] + red[2][t] + red[3][t];
    ud[t] = fminf(v - Dd[t], 0.f);
  }
  __syncthreads();
  int lane = t & 63, wave = t >> 6;
  if (wave < 4) {
    for (int o = wave; o < 10; o += 4) {
      float acc = 0.f;
      #pragma unroll
      for (int j = 0; j < 4; j++) {
        int ff = j*64 + lane;
        acc += ud[ff] * Wo[ff*10 + o];
      }
      #pragma unroll
      for (int off = 32; off; off >>= 1) acc += __shfl_down(acc, off, 64);
      if (lane == 0) out[b*10 + o] = Do[o] - acc;
    }
  }
}

extern "C" void kernel_launch(void* const* d_in, const int* in_sizes, int n_in,
                              void* d_out, int out_size, void* d_ws, size_t ws_size,
                              hipStream_t stream)
{
  float* outp = (float*)d_out;

  if (n_in != 13) { sentinel_k<<<5, 64, 0, stream>>>(outp, 200.f); return; }
  const int exp_sz[13] = {131072, 576, 576, 36864, 576, 73728, 1152,
                          147456, 1152, 8388608, 256, 2560, 10};
  for (int i = 0; i < 13; i++)
    if (in_sizes[i] != exp_sz[i]) {
      sentinel_k<<<5, 64, 0, stream>>>(outp, 1000.f + 100.f*i); return;
    }
  if (ws_size < (37u << 20)) { sentinel_k<<<5, 64, 0, stream>>>(outp, 500.f); return; }

  char* wsb = (char*)d_ws;
  const float* x    = (const float*)d_in[0];
  const float* Wc1  = (const float*)d_in[1];
  const float* Dc1  = (const float*)d_in[2];
  const float* Wc2  = (const float*)d_in[3];
  const float* Dc2  = (const float*)d_in[4];
  const float* Wc3  = (const float*)d_in[5];
  const float* Dc3  = (const float*)d_in[6];
  const float* Wc4  = (const float*)d_in[7];
  const float* Dc4  = (const float*)d_in[8];
  const float* Wd1  = (const float*)d_in[9];
  const float* Dd1  = (const float*)d_in[10];
  const float* Wout = (const float*)d_in[11];
  const float* Dout = (const float*)d_in[12];

  // ws layout (lifetime-safe):
  //   [1.0,1.8 MiB): Wt2/Wt3/Wt4 | U3/part=[2,11 MiB) | P2=[19,23.2) | P4=[25,27.1)
  // conv3 reads P2(19M) writes U3(2M); conv4 reads U3 writes P4(25M);
  // dense reads P4 writes part(2M, U3 dead).
  unsigned short* Wt2 = (unsigned short*)(wsb + (1u << 20));
  unsigned short* Wt3 = (unsigned short*)(wsb + (1u << 20) + 262144);
  unsigned short* Wt4 = (unsigned short*)(wsb + (1u << 20) + 524288);
  unsigned short* P2  = (unsigned short*)(wsb + (19u << 20)); // 4.2 MB
  unsigned short* U3  = (unsigned short*)(wsb + (2u  << 20)); // 8.4 MB
  unsigned short* P4  = (unsigned short*)(wsb + (25u << 20)); // 2.1 MB
  float* part         = (float*)(wsb + (2u  << 20));          // 8.4 MB

  wtrans_all<<<dim3(72, 3), 256, 0, stream>>>(Wc2, Wc3, Wc4, Wt2, Wt3, Wt4);
  conv12_k<<<dim3(32, 32), 256, 0, stream>>>(x, Wc1, Dc1, Wt2, Dc2, P2);
  conv_hf<64,  false><<<dim3(16, 32), 256, 0, stream>>>(P2, Wt3, Dc3, U3);
  conv_hf<128, true ><<<dim3(16, 32), 256, 0, stream>>>(U3, Wt4, Dc4, P4);
  dense_k<<<512, 256, 0, stream>>>(P4, Wd1, part);
  redfin_k<<<32, 1024, 0, stream>>>(part, Dd1, Wout, Dout, outp);
}